// Round 5
// baseline (276.279 us; speedup 1.0000x reference)
//
#include <hip/hip_runtime.h>
#include <math.h>

#define NQ   8192
#define MK   8192
#define KEEP 4096
#define NBLK 512
#define NTHR 256

// ---- ws byte offsets ----
#define OFF_BAR    0        // 64 B: (cnt,flag) pairs for 5 grid barriers (memset to 0 pre-launch)
#define OFF_KCNT   64       // 512 u32 per-block batch0 key counts
#define OFF_QCNT   2112     // 512 u32 per-block batch0 query counts
#define OFF_KPART  4160     // 8192 float4 partitioned keys  [batch0 | batch1], stable order
#define OFF_QPART  135232   // 8192 float4 partitioned queries {z,y,x,bits(idx)}
#define OFF_CMAX   266304   // 512*64 f32   chunk max per (group,chunk)
#define OFF_PART   397376   // 512*64 float4 chunk partials (l,sz,sy,sx)
#define OFF_K64    921664   // 8192 u64 sort keys (bits(imp)<<32)|idx
// total 987200 bytes

// out layout (floats):
//   [0,16384) coords | [16384,98304) voxels | [98304,102400) kept_imp
//   [102400,110592) importance

__device__ __forceinline__ float rdlanef(float v, int l) {
    return __int_as_float(__builtin_amdgcn_readlane(__float_as_int(v), l));
}

// sense-free single-use barrier per phase: counters pre-zeroed by hipMemsetAsync.
__device__ __forceinline__ void grid_barrier(unsigned* bar, int ph) {
    __syncthreads();
    if (threadIdx.x == 0) {
        __threadfence();
        unsigned prev = atomicAdd(bar + ph * 2, 1u);
        if (prev == NBLK - 1u) {
            atomicExch(bar + ph * 2 + 1, 1u);
        } else {
            while (atomicAdd(bar + ph * 2 + 1, 0u) == 0u) {
                __builtin_amdgcn_s_sleep(2);
            }
        }
        __threadfence();
    }
    __syncthreads();
}

__global__ __launch_bounds__(NTHR, 2) void fused_kernel(
    const int4*   __restrict__ vcoords,   // N x 4 [b,z,y,x]
    const float4* __restrict__ kcoords,   // M x 4 [b,z,y,x]
    const float*  __restrict__ voxels,    // N x 5 x 4
    const float*  __restrict__ w1, const float* __restrict__ b1,
    const float*  __restrict__ w2, const float* __restrict__ b2,
    float* __restrict__ out,
    void*  __restrict__ ws)
{
    __shared__ union {
        unsigned u32[2050];
        float    f32[2050];
        float4   f4[256];
    } sm;

    unsigned* bar   = (unsigned*)((char*)ws + OFF_BAR);
    unsigned* kcg   = (unsigned*)((char*)ws + OFF_KCNT);
    unsigned* qcg   = (unsigned*)((char*)ws + OFF_QCNT);
    float4*   kpart = (float4*)((char*)ws + OFF_KPART);
    float4*   qpart = (float4*)((char*)ws + OFF_QPART);
    float*    cmaxg = (float*)((char*)ws + OFF_CMAX);
    float4*   partg = (float4*)((char*)ws + OFF_PART);
    unsigned long long* K64g = (unsigned long long*)((char*)ws + OFF_K64);

    const int b = blockIdx.x, t = threadIdx.x;
    const int w = t >> 6, lane = t & 63;

    // ================= P0: per-block batch0 counts (16 keys + 16 queries) ====
    float4 myKey = make_float4(0.f, 0.f, 0.f, 0.f);
    int4   myQ   = make_int4(0, 0, 0, 0);
    bool   predb = false;
    if (t < 16)       { myKey = kcoords[b * 16 + t];        predb = (myKey.x == 0.0f); }
    else if (t < 32)  { myQ   = vcoords[b * 16 + (t - 16)]; predb = (myQ.x == 0); }
    unsigned long long ball = __ballot(predb);
    if (t == 0) {
        kcg[b] = (unsigned)__popcll(ball & 0xFFFFull);
        qcg[b] = (unsigned)__popcll((ball >> 16) & 0xFFFFull);
    }
    grid_barrier(bar, 0);

    // ================= P1: global prefix scan + stable partition scatter =====
    sm.u32[t]       = kcg[t];
    sm.u32[256 + t] = kcg[256 + t];
    sm.u32[512 + t] = qcg[t];
    sm.u32[768 + t] = qcg[256 + t];
    __syncthreads();
    if (w < 2) {
        unsigned* cnts = &sm.u32[w * 512];
        unsigned* pref = &sm.u32[1024 + w * 513];
        unsigned carry = 0;
        for (int r = 0; r < 8; ++r) {
            unsigned v = cnts[r * 64 + lane];
            unsigned sc = v;
            #pragma unroll
            for (int off = 1; off < 64; off <<= 1) {
                unsigned tv = __shfl_up(sc, off);
                if (lane >= off) sc += tv;
            }
            pref[r * 64 + lane] = carry + sc - v;   // exclusive prefix
            carry += __shfl(sc, 63);
        }
        if (lane == 0) pref[512] = carry;
    }
    __syncthreads();
    const int kOff = (int)sm.u32[1024 + b];
    const int kc0  = (int)sm.u32[1024 + 512];
    const int qOff = (int)sm.u32[1024 + 513 + b];
    const int qc0  = (int)sm.u32[1024 + 513 + 512];

    if (t < 16) {
        int gi = b * 16 + t;
        bool p0 = (myKey.x == 0.0f);
        int bef = (int)__popcll(ball & ((1ull << t) - 1));
        int dst = p0 ? (kOff + bef) : (kc0 + gi - (kOff + bef));
        kpart[dst] = myKey;
    } else if (t < 32) {
        int gi = b * 16 + (t - 16);
        bool p0 = (myQ.x == 0);
        int bef = (int)__popcll((ball >> 16) & ((1ull << (t - 16)) - 1));
        int dst = p0 ? (qOff + bef) : (qc0 + gi - (qOff + bef));
        qpart[dst] = make_float4((float)myQ.y, (float)myQ.z, (float)myQ.w,
                                 __int_as_float(gi));
    }
    grid_barrier(bar, 1);

    // ================= attention setup: block = (q-group g, key-chunk c) ====
    const int g = b >> 2, c = b & 3;
    const int slot = g * 64 + lane;
    const float4 q4 = qpart[slot];
    const float qz = q4.x, qy = q4.y, qx = q4.z;
    const bool wave_uniform = (g * 64 >= qc0) || (g * 64 + 64 <= qc0);
    const bool wb1 = (g * 64 >= qc0);
    const int r0  = wave_uniform ? (wb1 ? kc0 : 0) : 0;
    const int len = wave_uniform ? (wb1 ? (MK - kc0) : kc0) : MK;
    const float qbl = (slot >= qc0) ? 1.0f : 0.0f;
    const int s16 = c * 4 + w;                    // slice 0..15 of this group's range
    const int L  = (len + 15) >> 4;
    const int js = r0 + s16 * L;
    const int je = min(js + L, r0 + len);
    const float inv_sqrt3 = 0.57735026918962576f;

    // ================= P2: pass 1 — max of dot (register-broadcast) =========
    float mx = -INFINITY;
    for (int base = js; base < je; base += 64) {
        int li = base + lane;
        float4 kf = kpart[li < je ? li : (je - 1)];
        int nb = min(64, je - base);
        for (int i = 0; i < nb; ++i) {
            float ky = rdlanef(kf.y, i);
            float kz = rdlanef(kf.z, i);
            float kw = rdlanef(kf.w, i);
            float dot = fmaf(qz, ky, fmaf(qy, kz, qx * kw));
            if (!wave_uniform) {
                float kb = (base + i >= kc0) ? 1.0f : 0.0f;
                dot = fmaf(fabsf(kb - qbl), -1e10f, dot);
            }
            mx = fmaxf(mx, dot);
        }
    }
    sm.f32[w * 64 + lane] = mx;
    __syncthreads();
    if (w == 0) {
        float m4 = fmaxf(fmaxf(sm.f32[lane], sm.f32[64 + lane]),
                         fmaxf(sm.f32[128 + lane], sm.f32[192 + lane]));
        cmaxg[b * 64 + lane] = m4;
    }
    grid_barrier(bar, 2);

    // ================= P3: pass 2 — exp near global max ======================
    float mg = cmaxg[(g * 4 + 0) * 64 + lane];
    mg = fmaxf(mg, cmaxg[(g * 4 + 1) * 64 + lane]);
    mg = fmaxf(mg, cmaxg[(g * 4 + 2) * 64 + lane]);
    mg = fmaxf(mg, cmaxg[(g * 4 + 3) * 64 + lane]);
    const float cutoff = mg - 155.8845727f;       // 90*sqrt(3): sub-ulp beyond
    float accL = 0.f, szz = 0.f, syy = 0.f, sxx = 0.f;
    for (int base = js; base < je; base += 64) {
        int li = base + lane;
        float4 kf = kpart[li < je ? li : (je - 1)];
        int nb = min(64, je - base);
        for (int i = 0; i < nb; ++i) {
            float ky = rdlanef(kf.y, i);
            float kz = rdlanef(kf.z, i);
            float kw = rdlanef(kf.w, i);
            float dot = fmaf(qz, ky, fmaf(qy, kz, qx * kw));
            if (!wave_uniform) {
                float kb = (base + i >= kc0) ? 1.0f : 0.0f;
                dot = fmaf(fabsf(kb - qbl), -1e10f, dot);
            }
            bool take = (dot >= cutoff);
            if (__ballot(take)) {
                float e = take ? expf((dot - mg) * inv_sqrt3) : 0.f;
                accL += e;
                szz = fmaf(e, ky, szz);
                syy = fmaf(e, kz, syy);
                sxx = fmaf(e, kw, sxx);
            }
        }
    }
    __syncthreads();                              // sm reuse
    sm.f4[w * 64 + lane] = make_float4(accL, szz, syy, sxx);
    __syncthreads();
    if (w == 0) {
        float4 a = sm.f4[lane];
        #pragma unroll
        for (int ww = 1; ww < 4; ++ww) {
            float4 p = sm.f4[ww * 64 + lane];
            a.x += p.x; a.y += p.y; a.z += p.z; a.w += p.w;
        }
        partg[b * 64 + lane] = a;
    }
    grid_barrier(bar, 3);

    // ================= P4: chunk merge + MLP + K64 build =====================
    if (b < 32) {
        int s = b * 256 + t;                      // partitioned query slot
        int gg = s >> 6, ll = s & 63;
        float L4 = 0.f, SZ = 0.f, SY = 0.f, SX = 0.f;
        #pragma unroll
        for (int cc = 0; cc < 4; ++cc) {          // ascending chunk = ascending j
            float4 p = partg[(gg * 4 + cc) * 64 + ll];
            L4 += p.x; SZ += p.y; SY += p.z; SX += p.w;
        }
        float4 qq = qpart[s];
        int qid = __float_as_int(qq.w);
        float inv = (L4 > 0.f) ? 1.f / L4 : 0.f;
        float cz = SZ * inv, cy = SY * inv, cx = SX * inv;
        float logit = b2[0];
        #pragma unroll
        for (int k = 0; k < 32; ++k) {
            float h = b1[k] + cz * w1[k] + cy * w1[32 + k] + cx * w1[64 + k];
            h = fmaxf(h, 0.f);
            logit += h * w2[k];
        }
        float p = 1.f / (1.f + expf(-logit));
        out[102400 + qid] = p;
        K64g[qid] = ((unsigned long long)__float_as_uint(p) << 32) | (unsigned)qid;
    }
    grid_barrier(bar, 4);

    // ================= P5: rank (pairwise count) + scatter ===================
    // rank(i) = #{j: K_j < K_i}; K distinct => permutation == stable argsort.
    const int ib = b * 16;
    unsigned long long kiv = K64g[ib + (lane & 15)];
    unsigned kilo = (unsigned)kiv, kihi = (unsigned)(kiv >> 32);
    int accV = 0;
    const int jb0 = w * 2048;
    for (int half = 0; half < 2; ++half) {
        unsigned long long kj[16];
        int base = jb0 + half * 1024;
        #pragma unroll
        for (int r = 0; r < 16; ++r) kj[r] = K64g[base + r * 64 + lane];
        for (int i = 0; i < 16; ++i) {
            unsigned lo = (unsigned)__builtin_amdgcn_readlane((int)kilo, i);
            unsigned hi = (unsigned)__builtin_amdgcn_readlane((int)kihi, i);
            unsigned long long ki = ((unsigned long long)hi << 32) | lo;
            int cc = 0;
            #pragma unroll
            for (int r = 0; r < 16; ++r)
                cc += (int)__popcll(__ballot(kj[r] < ki));
            accV += (lane == i) ? cc : 0;
        }
    }
    __syncthreads();                              // sm reuse
    if (lane < 16) sm.u32[w * 16 + lane] = (unsigned)accV;
    __syncthreads();
    if (w == 0 && lane < 16) {
        int rank = 0;
        #pragma unroll
        for (int ww = 0; ww < 4; ++ww) rank += (int)sm.u32[ww * 16 + lane];
        if (rank >= KEEP) {
            int p = rank - KEEP;
            int iorig = ib + lane;
            int4 vc = vcoords[iorig];
            float4 c4;
            c4.x = (float)vc.x; c4.y = (float)vc.y;
            c4.z = (float)vc.z; c4.w = (float)vc.w;
            *(float4*)(out + p * 4) = c4;
            const float4* vs = (const float4*)(voxels + iorig * 20);
            float4* vd = (float4*)(out + 16384 + p * 20);
            #pragma unroll
            for (int k = 0; k < 5; ++k) vd[k] = vs[k];
            out[98304 + p] = __uint_as_float(kihi);
        }
    }
}

extern "C" void kernel_launch(void* const* d_in, const int* in_sizes, int n_in,
                              void* d_out, int out_size, void* d_ws, size_t ws_size,
                              hipStream_t stream) {
    const int4*   vcoords = (const int4*)d_in[0];
    const float4* kcoords = (const float4*)d_in[1];
    const float*  voxels  = (const float*)d_in[2];
    const float*  w1      = (const float*)d_in[3];
    const float*  b1      = (const float*)d_in[4];
    const float*  w2      = (const float*)d_in[5];
    const float*  b2      = (const float*)d_in[6];
    float* out = (float*)d_out;

    hipMemsetAsync(d_ws, 0, 64, stream);          // zero grid-barrier state
    fused_kernel<<<NBLK, NTHR, 0, stream>>>(vcoords, kcoords, voxels,
                                            w1, b1, w2, b2, out, d_ws);
}

// Round 6
// 123.067 us; speedup vs baseline: 2.2449x; 2.2449x over previous
//
#include <hip/hip_runtime.h>
#include <math.h>

#define NQ   8192
#define MK   8192
#define KEEP 4096

// ---- ws byte offsets ----
#define OFF_HDR    0                       // 4 ints {kc0, kc1, qc0, qc1}
#define OFF_KPART  64                      // 8192 float4 partitioned keys {b,z,y,x}
#define OFF_QPART  (OFF_KPART + 131072)    // 8192 float4 queries {z,y,x,idx_bits}
#define OFF_CMAX   (OFF_QPART + 131072)    // 64*4*128 f32 chunk maxes
#define OFF_PART   (OFF_CMAX  + 131072)    // 64*4*128 float4 chunk partials
#define OFF_K64    (OFF_PART  + 524288)    // 8192 u64 sort keys
// total 983104 B (< R5's 987200 which fit)

// out layout (floats):
//   [0,16384) coords | [16384,98304) voxels | [98304,102400) kept_imp
//   [102400,110592) importance

typedef unsigned long long ull;

// ------------------------------------------------- partition (verbatim R3)
__global__ __launch_bounds__(1024) void partition_kernel(
    const int4*   __restrict__ vcoords,
    const float4* __restrict__ kcoords,
    float* __restrict__ ws)
{
    __shared__ int wtot[16];
    const int t = threadIdx.x, w = t >> 6, lane = t & 63;
    const int base = t * 8;
    int* hdr = (int*)ws;
    float4* kp = (float4*)((char*)ws + OFF_KPART);
    float4* qp = (float4*)((char*)ws + OFF_QPART);

    // ---- keys ----
    float4 kv[8];
    int n0 = 0;
    #pragma unroll
    for (int r = 0; r < 8; ++r) { kv[r] = kcoords[base + r]; n0 += (kv[r].x == 0.0f) ? 1 : 0; }
    int inc = n0;
    #pragma unroll
    for (int off = 1; off < 64; off <<= 1) { int a = __shfl_up(inc, off); if (lane >= off) inc += a; }
    if (lane == 63) wtot[w] = inc;
    __syncthreads();
    int wbase = 0, tot0 = 0;
    #pragma unroll
    for (int i = 0; i < 16; ++i) { if (i < w) wbase += wtot[i]; tot0 += wtot[i]; }
    int ex0 = wbase + inc - n0;
    int ex1 = tot0 + (base - ex0);
    #pragma unroll
    for (int r = 0; r < 8; ++r) {
        if (kv[r].x == 0.0f) kp[ex0++] = kv[r]; else kp[ex1++] = kv[r];
    }
    if (t == 0) { hdr[0] = tot0; hdr[1] = MK - tot0; }
    __syncthreads();                      // protect wtot reuse

    // ---- queries ----
    int4 qv[8];
    int qn0 = 0;
    #pragma unroll
    for (int r = 0; r < 8; ++r) { qv[r] = vcoords[base + r]; qn0 += (qv[r].x == 0) ? 1 : 0; }
    int qinc = qn0;
    #pragma unroll
    for (int off = 1; off < 64; off <<= 1) { int a = __shfl_up(qinc, off); if (lane >= off) qinc += a; }
    if (lane == 63) wtot[w] = qinc;
    __syncthreads();
    int qwbase = 0, qtot0 = 0;
    #pragma unroll
    for (int i = 0; i < 16; ++i) { if (i < w) qwbase += wtot[i]; qtot0 += wtot[i]; }
    int qex0 = qwbase + qinc - qn0;
    int qex1 = qtot0 + (base - qex0);
    #pragma unroll
    for (int r = 0; r < 8; ++r) {
        int idx = base + r;
        float4 q;
        q.x = (float)qv[r].y; q.y = (float)qv[r].z; q.z = (float)qv[r].w;
        q.w = __int_as_float(idx);
        if (qv[r].x == 0) qp[qex0++] = q; else qp[qex1++] = q;
    }
    if (t == 0) { hdr[2] = qtot0; hdr[3] = NQ - qtot0; }
}

// block = (q-group g of 128 queries, key-chunk c of 4). 16 waves share the
// same 128 queries (2/thread); wave w scans its 1/16 slice of the chunk via
// uniform ds_read_b128 broadcast. One LDS read feeds 128 dots.
__device__ __forceinline__ void chunk_geom(const int* hdr, int b,
    int& g, int& cs, int& tn, bool& uni, int& qc0, int& kc0)
{
    kc0 = hdr[0]; qc0 = hdr[2];
    g = b >> 2; const int c = b & 3;
    const int gs = g * 128;
    const bool uni1 = (gs >= qc0);
    uni = (gs + 128 <= qc0) || uni1;
    const int r0  = (uni && uni1) ? kc0 : 0;
    const int len = uni ? (uni1 ? MK - kc0 : kc0) : MK;
    const int CL = (len + 3) >> 2;
    cs = r0 + c * CL;
    tn = min(cs + CL, r0 + len) - cs;
    if (tn < 0) tn = 0;
}

// ------------------------------------------------- pass 1: masked max
__global__ __launch_bounds__(1024) void max_kernel(float* __restrict__ ws)
{
    __shared__ float4 sk[2048];           // 32 KB
    __shared__ float red[16][128];        // 8 KB
    const int* hdr = (const int*)ws;
    const float4* kpart = (const float4*)((char*)ws + OFF_KPART);
    const float4* qpart = (const float4*)((char*)ws + OFF_QPART);
    float* cmax = (float*)((char*)ws + OFF_CMAX);

    int g, cs, tn, qc0, kc0; bool uni;
    chunk_geom(hdr, blockIdx.x, g, cs, tn, uni, qc0, kc0);

    const int t = threadIdx.x, w = t >> 6, lane = t & 63;
    const int s0 = g * 128 + lane, s1 = s0 + 64;
    const float4 qa = qpart[s0], qb = qpart[s1];
    const float qbl0 = (s0 >= qc0) ? 1.f : 0.f;
    const float qbl1 = (s1 >= qc0) ? 1.f : 0.f;

    for (int j = t; j < tn; j += 1024) sk[j] = kpart[cs + j];
    __syncthreads();

    const int SL = (tn + 15) >> 4;
    const int jb = w * SL, je = min(jb + SL, tn);

    float m0 = -INFINITY, m1 = -INFINITY;
    if (uni) {
        #pragma unroll 4
        for (int j = jb; j < je; ++j) {
            float4 k4 = sk[j];
            float d0 = fmaf(qa.x, k4.y, fmaf(qa.y, k4.z, qa.z * k4.w));
            float d1 = fmaf(qb.x, k4.y, fmaf(qb.y, k4.z, qb.z * k4.w));
            m0 = fmaxf(m0, d0); m1 = fmaxf(m1, d1);
        }
    } else {
        #pragma unroll 4
        for (int j = jb; j < je; ++j) {
            float4 k4 = sk[j];
            float d0 = fmaf(qa.x, k4.y, fmaf(qa.y, k4.z, qa.z * k4.w));
            float d1 = fmaf(qb.x, k4.y, fmaf(qb.y, k4.z, qb.z * k4.w));
            d0 = fmaf(fabsf(k4.x - qbl0), -1e10f, d0);
            d1 = fmaf(fabsf(k4.x - qbl1), -1e10f, d1);
            m0 = fmaxf(m0, d0); m1 = fmaxf(m1, d1);
        }
    }
    red[w][lane] = m0; red[w][64 + lane] = m1;
    __syncthreads();
    if (t < 128) {
        float m = red[0][t];
        #pragma unroll
        for (int i = 1; i < 16; ++i) m = fmaxf(m, red[i][t]);
        cmax[(blockIdx.x) * 128 + t] = m;   // (g*4+c)*128 + q
    }
}

// ------------------------------------------------- pass 2: exp near max
__global__ __launch_bounds__(1024) void exp_kernel(float* __restrict__ ws)
{
    __shared__ float4 sk[2048];           // 32 KB
    __shared__ float4 pf[16 * 128];       // 32 KB
    const int* hdr = (const int*)ws;
    const float4* kpart = (const float4*)((char*)ws + OFF_KPART);
    const float4* qpart = (const float4*)((char*)ws + OFF_QPART);
    const float* cmax = (const float*)((char*)ws + OFF_CMAX);
    float4* partg = (float4*)((char*)ws + OFF_PART);

    int g, cs, tn, qc0, kc0; bool uni;
    chunk_geom(hdr, blockIdx.x, g, cs, tn, uni, qc0, kc0);

    const int t = threadIdx.x, w = t >> 6, lane = t & 63;
    const int s0 = g * 128 + lane, s1 = s0 + 64;
    const float4 qa = qpart[s0], qb = qpart[s1];
    const float qbl0 = (s0 >= qc0) ? 1.f : 0.f;
    const float qbl1 = (s1 >= qc0) ? 1.f : 0.f;
    const float inv_sqrt3 = 0.57735026918962576f;

    float mg0 = cmax[g * 512 + lane];
    float mg1 = cmax[g * 512 + 64 + lane];
    #pragma unroll
    for (int cc = 1; cc < 4; ++cc) {
        mg0 = fmaxf(mg0, cmax[g * 512 + cc * 128 + lane]);
        mg1 = fmaxf(mg1, cmax[g * 512 + cc * 128 + 64 + lane]);
    }
    const float cut0 = mg0 - 155.8845727f;   // 90*sqrt(3): sub-ulp beyond
    const float cut1 = mg1 - 155.8845727f;

    for (int j = t; j < tn; j += 1024) sk[j] = kpart[cs + j];
    __syncthreads();

    const int SL = (tn + 15) >> 4;
    const int jb = w * SL, je = min(jb + SL, tn);

    float l0 = 0.f, sz0 = 0.f, sy0 = 0.f, sx0 = 0.f;
    float l1 = 0.f, sz1 = 0.f, sy1 = 0.f, sx1 = 0.f;
    #pragma unroll 4
    for (int j = jb; j < je; ++j) {
        float4 k4 = sk[j];
        float d0 = fmaf(qa.x, k4.y, fmaf(qa.y, k4.z, qa.z * k4.w));
        float d1 = fmaf(qb.x, k4.y, fmaf(qb.y, k4.z, qb.z * k4.w));
        if (!uni) {
            d0 = fmaf(fabsf(k4.x - qbl0), -1e10f, d0);
            d1 = fmaf(fabsf(k4.x - qbl1), -1e10f, d1);
        }
        bool t0 = (d0 >= cut0), t1 = (d1 >= cut1);
        if (__any(t0 || t1)) {
            float e0 = t0 ? expf((d0 - mg0) * inv_sqrt3) : 0.f;
            float e1 = t1 ? expf((d1 - mg1) * inv_sqrt3) : 0.f;
            l0 += e0; sz0 = fmaf(e0, k4.y, sz0); sy0 = fmaf(e0, k4.z, sy0); sx0 = fmaf(e0, k4.w, sx0);
            l1 += e1; sz1 = fmaf(e1, k4.y, sz1); sy1 = fmaf(e1, k4.z, sy1); sx1 = fmaf(e1, k4.w, sx1);
        }
    }
    pf[w * 128 + lane]      = make_float4(l0, sz0, sy0, sx0);
    pf[w * 128 + 64 + lane] = make_float4(l1, sz1, sy1, sx1);
    __syncthreads();
    if (t < 128) {
        float4 a = pf[t];
        #pragma unroll
        for (int i = 1; i < 16; ++i) {      // ascending wave = ascending j
            float4 p = pf[i * 128 + t];
            a.x += p.x; a.y += p.y; a.z += p.z; a.w += p.w;
        }
        partg[blockIdx.x * 128 + t] = a;
    }
}

// ------------------------------------------------- chunk merge + MLP + K64
__global__ __launch_bounds__(256) void mlp_kernel(
    const float* __restrict__ ws,
    const float* __restrict__ w1, const float* __restrict__ b1,
    const float* __restrict__ w2, const float* __restrict__ b2,
    float* __restrict__ out_imp, ull* __restrict__ K64)
{
    const int s = blockIdx.x * 256 + threadIdx.x;
    const int g = s >> 7, q = s & 127;
    const float4* partg = (const float4*)((const char*)ws + OFF_PART);
    const float4* qpart = (const float4*)((const char*)ws + OFF_QPART);

    float L = 0.f, SZ = 0.f, SY = 0.f, SX = 0.f;
    #pragma unroll
    for (int cc = 0; cc < 4; ++cc) {        // ascending chunk = ascending j
        float4 p = partg[(g * 4 + cc) * 128 + q];
        L += p.x; SZ += p.y; SY += p.z; SX += p.w;
    }
    const float4 qq = qpart[s];
    const int qid = __float_as_int(qq.w);
    float inv = (L > 0.f) ? 1.f / L : 0.f;
    float cz = SZ * inv, cy = SY * inv, cx = SX * inv;
    float logit = b2[0];
    #pragma unroll
    for (int k = 0; k < 32; ++k) {
        float h = b1[k] + cz * w1[k] + cy * w1[32 + k] + cx * w1[64 + k];
        h = fmaxf(h, 0.f);
        logit += h * w2[k];
    }
    float p = 1.f / (1.f + expf(-logit));
    out_imp[qid] = p;
    K64[qid] = ((ull)__float_as_uint(p) << 32) | (unsigned)qid;
}

// ------------------------------------------------- rank + scatter
// rank(i) = #{j: K_j < K_i}; distinct keys => permutation == stable argsort.
// 256 blocks x 1024: block = 32 i's, wave = 512 j's in regs, ballot transpose.
__global__ __launch_bounds__(1024) void rank_scatter_kernel(
    const ull* __restrict__ K,
    const int4* __restrict__ vcoords,
    const float* __restrict__ voxels,
    float* __restrict__ out)
{
    __shared__ int scnt[16][32];
    __shared__ int rks[32];
    const int t = threadIdx.x, w = t >> 6, lane = t & 63;
    const int ib = blockIdx.x * 32;

    const ull kiv = K[ib + (lane & 31)];
    const int kilo = (int)(unsigned)kiv, kihi = (int)(unsigned)(kiv >> 32);

    const int jb = w * 512;
    ull kj[8];
    #pragma unroll
    for (int r = 0; r < 8; ++r) kj[r] = K[jb + r * 64 + lane];

    int acc = 0;
    for (int i = 0; i < 32; ++i) {
        unsigned lo = (unsigned)__builtin_amdgcn_readlane(kilo, i);
        unsigned hi = (unsigned)__builtin_amdgcn_readlane(kihi, i);
        ull ki = ((ull)hi << 32) | lo;
        int c = 0;
        #pragma unroll
        for (int r = 0; r < 8; ++r)
            c += (int)__popcll(__ballot(kj[r] < ki));
        acc += (lane == i) ? c : 0;
    }
    if (lane < 32) scnt[w][lane] = acc;
    __syncthreads();
    if (t < 32) {
        int rank = 0;
        #pragma unroll
        for (int ww = 0; ww < 16; ++ww) rank += scnt[ww][t];
        rks[t] = rank;
    }
    __syncthreads();

    // cooperative scatter: 32 threads per kept row
    const int il = t >> 5, r = t & 31;
    const int rank = rks[il];
    if (rank >= KEEP) {
        const int p = rank - KEEP;
        const int i = ib + il;
        if (r < 20) {
            out[16384 + p * 20 + r] = voxels[i * 20 + r];
        } else if (r < 24) {
            const int* vc = (const int*)&vcoords[i];
            out[p * 4 + (r - 20)] = (float)vc[r - 20];
        } else if (r == 24) {
            out[98304 + p] = __uint_as_float((unsigned)(K[i] >> 32));
        }
    }
}

extern "C" void kernel_launch(void* const* d_in, const int* in_sizes, int n_in,
                              void* d_out, int out_size, void* d_ws, size_t ws_size,
                              hipStream_t stream) {
    const int4*   vcoords = (const int4*)d_in[0];
    const float4* kcoords = (const float4*)d_in[1];
    const float*  voxels  = (const float*)d_in[2];
    const float*  w1      = (const float*)d_in[3];
    const float*  b1      = (const float*)d_in[4];
    const float*  w2      = (const float*)d_in[5];
    const float*  b2      = (const float*)d_in[6];
    float* out = (float*)d_out;
    float* ws  = (float*)d_ws;
    ull* K64   = (ull*)((char*)d_ws + OFF_K64);

    partition_kernel<<<1, 1024, 0, stream>>>(vcoords, kcoords, ws);
    max_kernel<<<256, 1024, 0, stream>>>(ws);
    exp_kernel<<<256, 1024, 0, stream>>>(ws);
    mlp_kernel<<<32, 256, 0, stream>>>(ws, w1, b1, w2, b2, out + 102400, K64);
    rank_scatter_kernel<<<256, 1024, 0, stream>>>(K64, vcoords, voxels, out);
}

// Round 7
// 118.940 us; speedup vs baseline: 2.3228x; 1.0347x over previous
//
#include <hip/hip_runtime.h>
#include <math.h>

#define NQ   8192
#define MK   8192
#define KEEP 4096

// ---- ws byte offsets ----
#define OFF_HDR    0                        // 4 ints {kc0, kc1, qc0, qc1}
#define OFF_KPART  64                       // 8192 float4 partitioned keys {b,z,y,x}
#define OFF_QPART  131136                   // 8192 float4 queries {z,y,x,idx_bits}
#define OFF_CMAX   262208                   // 256 blk x 256 q  f32 chunk max
#define OFF_PART   524352                   // 256 blk x 256 q  float4 chunk partials
#define OFF_K64    1572928                  // 8192 u64 sort keys

// out layout (floats):
//   [0,16384) coords | [16384,98304) voxels | [98304,102400) kept_imp
//   [102400,110592) importance

typedef unsigned long long ull;

// ------------------------------------------------- partition (verbatim R3/R6)
__global__ __launch_bounds__(1024) void partition_kernel(
    const int4*   __restrict__ vcoords,
    const float4* __restrict__ kcoords,
    float* __restrict__ ws)
{
    __shared__ int wtot[16];
    const int t = threadIdx.x, w = t >> 6, lane = t & 63;
    const int base = t * 8;
    int* hdr = (int*)ws;
    float4* kp = (float4*)((char*)ws + OFF_KPART);
    float4* qp = (float4*)((char*)ws + OFF_QPART);

    float4 kv[8];
    int n0 = 0;
    #pragma unroll
    for (int r = 0; r < 8; ++r) { kv[r] = kcoords[base + r]; n0 += (kv[r].x == 0.0f) ? 1 : 0; }
    int inc = n0;
    #pragma unroll
    for (int off = 1; off < 64; off <<= 1) { int a = __shfl_up(inc, off); if (lane >= off) inc += a; }
    if (lane == 63) wtot[w] = inc;
    __syncthreads();
    int wbase = 0, tot0 = 0;
    #pragma unroll
    for (int i = 0; i < 16; ++i) { if (i < w) wbase += wtot[i]; tot0 += wtot[i]; }
    int ex0 = wbase + inc - n0;
    int ex1 = tot0 + (base - ex0);
    #pragma unroll
    for (int r = 0; r < 8; ++r) {
        if (kv[r].x == 0.0f) kp[ex0++] = kv[r]; else kp[ex1++] = kv[r];
    }
    if (t == 0) { hdr[0] = tot0; hdr[1] = MK - tot0; }
    __syncthreads();

    int4 qv[8];
    int qn0 = 0;
    #pragma unroll
    for (int r = 0; r < 8; ++r) { qv[r] = vcoords[base + r]; qn0 += (qv[r].x == 0) ? 1 : 0; }
    int qinc = qn0;
    #pragma unroll
    for (int off = 1; off < 64; off <<= 1) { int a = __shfl_up(qinc, off); if (lane >= off) qinc += a; }
    if (lane == 63) wtot[w] = qinc;
    __syncthreads();
    int qwbase = 0, qtot0 = 0;
    #pragma unroll
    for (int i = 0; i < 16; ++i) { if (i < w) qwbase += wtot[i]; qtot0 += wtot[i]; }
    int qex0 = qwbase + qinc - qn0;
    int qex1 = qtot0 + (base - qex0);
    #pragma unroll
    for (int r = 0; r < 8; ++r) {
        int idx = base + r;
        float4 q;
        q.x = (float)qv[r].y; q.y = (float)qv[r].z; q.z = (float)qv[r].w;
        q.w = __int_as_float(idx);
        if (qv[r].x == 0) qp[qex0++] = q; else qp[qex1++] = q;
    }
    if (t == 0) { hdr[2] = qtot0; hdr[3] = NQ - qtot0; }
}

// ------------------------------------------------- fused attention
// block = (q-group g of 256 queries, key-chunk c of 8). 16 waves share the
// same 256 queries (4/thread); each wave scans its 1/16 slice of the chunk
// TWICE from LDS (pass1 chunk-local max, pass2 exp vs chunk max). One
// ds_read_b128 broadcast feeds 256 dots. Chunk-local softmax shift c is
// exact up to normalization: merge kernel rescales by exp((c-C)/sqrt3);
// masked-chunk garbage (c ~ -1e10) is annihilated there (exp -> 0).
__global__ __launch_bounds__(1024) void attn_kernel(float* __restrict__ ws)
{
    __shared__ __align__(16) char smem[65792];
    float4* sk   = (float4*)smem;                     // [0, 16384)
    float*  red1 = (float*)(smem + 16384);            // 16 x 257 f32
    float*  red2 = (float*)(smem + 16384 + 16448);    // 256 f32 (ends 33856)
    float4* pf   = (float4*)smem;                     // 16 x 257 float4 (reuses all)

    const int* hdr = (const int*)ws;
    const float4* kpart = (const float4*)((char*)ws + OFF_KPART);
    const float4* qpart = (const float4*)((char*)ws + OFF_QPART);
    float*  cmaxg = (float*)((char*)ws + OFF_CMAX);
    float4* partg = (float4*)((char*)ws + OFF_PART);

    const int kc0 = hdr[0], qc0 = hdr[2];
    const int g = blockIdx.x >> 3, c = blockIdx.x & 7;
    const int gs = g * 256;
    const bool uni1 = (gs >= qc0);
    const bool uni  = (gs + 256 <= qc0) || uni1;
    const int r0  = (uni && uni1) ? kc0 : 0;
    const int len = uni ? (uni1 ? MK - kc0 : kc0) : MK;
    const int CL = (len + 7) >> 3;
    const int cs = r0 + c * CL;
    int tn = min(cs + CL, r0 + len) - cs; if (tn < 0) tn = 0;

    const int t = threadIdx.x, w = t >> 6, lane = t & 63;
    const float4 q0 = qpart[gs + lane];
    const float4 q1 = qpart[gs + lane + 64];
    const float4 q2 = qpart[gs + lane + 128];
    const float4 q3 = qpart[gs + lane + 192];
    const float b0 = (gs + lane        >= qc0) ? 1.f : 0.f;
    const float b1 = (gs + lane + 64   >= qc0) ? 1.f : 0.f;
    const float b2_ = (gs + lane + 128 >= qc0) ? 1.f : 0.f;
    const float b3 = (gs + lane + 192  >= qc0) ? 1.f : 0.f;
    const float is3 = 0.57735026918962576f;

    if (t < tn) sk[t] = kpart[cs + t];
    __syncthreads();

    const int SL = (tn + 15) >> 4;
    const int jb = w * SL, je = min(jb + SL, tn);

    // ---- pass 1: chunk-local max ----
    float m0 = -INFINITY, m1 = -INFINITY, m2 = -INFINITY, m3 = -INFINITY;
    if (uni) {
        #pragma unroll 4
        for (int j = jb; j < je; ++j) {
            float4 k4 = sk[j];
            m0 = fmaxf(m0, fmaf(q0.x, k4.y, fmaf(q0.y, k4.z, q0.z * k4.w)));
            m1 = fmaxf(m1, fmaf(q1.x, k4.y, fmaf(q1.y, k4.z, q1.z * k4.w)));
            m2 = fmaxf(m2, fmaf(q2.x, k4.y, fmaf(q2.y, k4.z, q2.z * k4.w)));
            m3 = fmaxf(m3, fmaf(q3.x, k4.y, fmaf(q3.y, k4.z, q3.z * k4.w)));
        }
    } else {
        #pragma unroll 4
        for (int j = jb; j < je; ++j) {
            float4 k4 = sk[j];
            float d0 = fmaf(q0.x, k4.y, fmaf(q0.y, k4.z, q0.z * k4.w));
            float d1 = fmaf(q1.x, k4.y, fmaf(q1.y, k4.z, q1.z * k4.w));
            float d2 = fmaf(q2.x, k4.y, fmaf(q2.y, k4.z, q2.z * k4.w));
            float d3 = fmaf(q3.x, k4.y, fmaf(q3.y, k4.z, q3.z * k4.w));
            m0 = fmaxf(m0, fmaf(fabsf(k4.x - b0),  -1e10f, d0));
            m1 = fmaxf(m1, fmaf(fabsf(k4.x - b1),  -1e10f, d1));
            m2 = fmaxf(m2, fmaf(fabsf(k4.x - b2_), -1e10f, d2));
            m3 = fmaxf(m3, fmaf(fabsf(k4.x - b3),  -1e10f, d3));
        }
    }
    red1[w * 257 + lane]       = m0;
    red1[w * 257 + lane + 64]  = m1;
    red1[w * 257 + lane + 128] = m2;
    red1[w * 257 + lane + 192] = m3;
    __syncthreads();
    {
        const int col = t >> 2, r4 = (t & 3) * 4;
        float mv = red1[r4 * 257 + col];
        mv = fmaxf(mv, red1[(r4 + 1) * 257 + col]);
        mv = fmaxf(mv, red1[(r4 + 2) * 257 + col]);
        mv = fmaxf(mv, red1[(r4 + 3) * 257 + col]);
        mv = fmaxf(mv, __shfl_xor(mv, 1));
        mv = fmaxf(mv, __shfl_xor(mv, 2));
        if ((t & 3) == 0) {
            red2[col] = mv;
            cmaxg[blockIdx.x * 256 + col] = mv;
        }
    }
    __syncthreads();
    const float mg0 = red2[lane],       cut0 = mg0 - 155.8845727f;
    const float mg1 = red2[lane + 64],  cut1 = mg1 - 155.8845727f;
    const float mg2 = red2[lane + 128], cut2 = mg2 - 155.8845727f;
    const float mg3 = red2[lane + 192], cut3 = mg3 - 155.8845727f;

    // ---- pass 2: exp near chunk max ----
    float l0 = 0.f, sz0 = 0.f, sy0 = 0.f, sx0 = 0.f;
    float l1 = 0.f, sz1 = 0.f, sy1 = 0.f, sx1 = 0.f;
    float l2 = 0.f, sz2 = 0.f, sy2 = 0.f, sx2 = 0.f;
    float l3 = 0.f, sz3 = 0.f, sy3 = 0.f, sx3 = 0.f;
    #pragma unroll 2
    for (int j = jb; j < je; ++j) {
        float4 k4 = sk[j];
        float d0 = fmaf(q0.x, k4.y, fmaf(q0.y, k4.z, q0.z * k4.w));
        float d1 = fmaf(q1.x, k4.y, fmaf(q1.y, k4.z, q1.z * k4.w));
        float d2 = fmaf(q2.x, k4.y, fmaf(q2.y, k4.z, q2.z * k4.w));
        float d3 = fmaf(q3.x, k4.y, fmaf(q3.y, k4.z, q3.z * k4.w));
        if (!uni) {
            d0 = fmaf(fabsf(k4.x - b0),  -1e10f, d0);
            d1 = fmaf(fabsf(k4.x - b1),  -1e10f, d1);
            d2 = fmaf(fabsf(k4.x - b2_), -1e10f, d2);
            d3 = fmaf(fabsf(k4.x - b3),  -1e10f, d3);
        }
        bool t0 = d0 >= cut0, t1 = d1 >= cut1, t2 = d2 >= cut2, t3 = d3 >= cut3;
        if (__any(t0 || t1 || t2 || t3)) {
            float e0 = t0 ? expf((d0 - mg0) * is3) : 0.f;
            float e1 = t1 ? expf((d1 - mg1) * is3) : 0.f;
            float e2 = t2 ? expf((d2 - mg2) * is3) : 0.f;
            float e3 = t3 ? expf((d3 - mg3) * is3) : 0.f;
            l0 += e0; sz0 = fmaf(e0, k4.y, sz0); sy0 = fmaf(e0, k4.z, sy0); sx0 = fmaf(e0, k4.w, sx0);
            l1 += e1; sz1 = fmaf(e1, k4.y, sz1); sy1 = fmaf(e1, k4.z, sy1); sx1 = fmaf(e1, k4.w, sx1);
            l2 += e2; sz2 = fmaf(e2, k4.y, sz2); sy2 = fmaf(e2, k4.z, sy2); sx2 = fmaf(e2, k4.w, sx2);
            l3 += e3; sz3 = fmaf(e3, k4.y, sz3); sy3 = fmaf(e3, k4.z, sy3); sx3 = fmaf(e3, k4.w, sx3);
        }
    }
    __syncthreads();                       // all sk reads done; pf may clobber
    pf[w * 257 + lane]       = make_float4(l0, sz0, sy0, sx0);
    pf[w * 257 + lane + 64]  = make_float4(l1, sz1, sy1, sx1);
    pf[w * 257 + lane + 128] = make_float4(l2, sz2, sy2, sx2);
    pf[w * 257 + lane + 192] = make_float4(l3, sz3, sy3, sx3);
    __syncthreads();
    {
        const int col = t >> 2, r4 = (t & 3) * 4;
        float4 a = pf[r4 * 257 + col];
        #pragma unroll
        for (int rr = 1; rr < 4; ++rr) {
            float4 p = pf[(r4 + rr) * 257 + col];
            a.x += p.x; a.y += p.y; a.z += p.z; a.w += p.w;
        }
        a.x += __shfl_xor(a.x, 1); a.y += __shfl_xor(a.y, 1);
        a.z += __shfl_xor(a.z, 1); a.w += __shfl_xor(a.w, 1);
        a.x += __shfl_xor(a.x, 2); a.y += __shfl_xor(a.y, 2);
        a.z += __shfl_xor(a.z, 2); a.w += __shfl_xor(a.w, 2);
        if ((t & 3) == 0) partg[blockIdx.x * 256 + col] = a;
    }
}

// ------------------------------------------------- chunk merge + MLP + K64
__global__ __launch_bounds__(256) void mlp_kernel(
    const float* __restrict__ ws,
    const float* __restrict__ w1, const float* __restrict__ b1,
    const float* __restrict__ w2, const float* __restrict__ b2,
    float* __restrict__ out_imp, ull* __restrict__ K64)
{
    const int s = blockIdx.x * 256 + threadIdx.x;
    const int g = s >> 8, q = s & 255;
    const float*  cmaxg = (const float*)((const char*)ws + OFF_CMAX);
    const float4* partg = (const float4*)((const char*)ws + OFF_PART);
    const float4* qpart = (const float4*)((const char*)ws + OFF_QPART);
    const float is3 = 0.57735026918962576f;

    float cc[8];
    float C = -INFINITY;
    #pragma unroll
    for (int c = 0; c < 8; ++c) {
        cc[c] = cmaxg[(g * 8 + c) * 256 + q];
        C = fmaxf(C, cc[c]);
    }
    float L = 0.f, SZ = 0.f, SY = 0.f, SX = 0.f;
    if (C != -INFINITY) {
        #pragma unroll
        for (int c = 0; c < 8; ++c) {      // ascending chunk: deterministic
            float sc = expf((cc[c] - C) * is3);   // kills masked-chunk garbage
            float4 p = partg[(g * 8 + c) * 256 + q];
            L  = fmaf(p.x, sc, L);
            SZ = fmaf(p.y, sc, SZ);
            SY = fmaf(p.z, sc, SY);
            SX = fmaf(p.w, sc, SX);
        }
    }
    const float4 qq = qpart[s];
    const int qid = __float_as_int(qq.w);
    float inv = (L > 0.f) ? 1.f / L : 0.f;
    float cz = SZ * inv, cy = SY * inv, cx = SX * inv;
    float logit = b2[0];
    #pragma unroll
    for (int k = 0; k < 32; ++k) {
        float h = b1[k] + cz * w1[k] + cy * w1[32 + k] + cx * w1[64 + k];
        h = fmaxf(h, 0.f);
        logit += h * w2[k];
    }
    float p = 1.f / (1.f + expf(-logit));
    out_imp[qid] = p;
    K64[qid] = ((ull)__float_as_uint(p) << 32) | (unsigned)qid;
}

// ------------------------------------------------- rank + scatter (R6)
__global__ __launch_bounds__(1024) void rank_scatter_kernel(
    const ull* __restrict__ K,
    const int4* __restrict__ vcoords,
    const float* __restrict__ voxels,
    float* __restrict__ out)
{
    __shared__ int scnt[16][32];
    __shared__ int rks[32];
    const int t = threadIdx.x, w = t >> 6, lane = t & 63;
    const int ib = blockIdx.x * 32;

    const ull kiv = K[ib + (lane & 31)];
    const int kilo = (int)(unsigned)kiv, kihi = (int)(unsigned)(kiv >> 32);

    const int jb = w * 512;
    ull kj[8];
    #pragma unroll
    for (int r = 0; r < 8; ++r) kj[r] = K[jb + r * 64 + lane];

    int acc = 0;
    for (int i = 0; i < 32; ++i) {
        unsigned lo = (unsigned)__builtin_amdgcn_readlane(kilo, i);
        unsigned hi = (unsigned)__builtin_amdgcn_readlane(kihi, i);
        ull ki = ((ull)hi << 32) | lo;
        int c = 0;
        #pragma unroll
        for (int r = 0; r < 8; ++r)
            c += (int)__popcll(__ballot(kj[r] < ki));
        acc += (lane == i) ? c : 0;
    }
    if (lane < 32) scnt[w][lane] = acc;
    __syncthreads();
    if (t < 32) {
        int rank = 0;
        #pragma unroll
        for (int ww = 0; ww < 16; ++ww) rank += scnt[ww][t];
        rks[t] = rank;
    }
    __syncthreads();

    const int il = t >> 5, r = t & 31;
    const int rank = rks[il];
    if (rank >= KEEP) {
        const int p = rank - KEEP;
        const int i = ib + il;
        if (r < 20) {
            out[16384 + p * 20 + r] = voxels[i * 20 + r];
        } else if (r < 24) {
            const int* vc = (const int*)&vcoords[i];
            out[p * 4 + (r - 20)] = (float)vc[r - 20];
        } else if (r == 24) {
            out[98304 + p] = __uint_as_float((unsigned)(K[i] >> 32));
        }
    }
}

extern "C" void kernel_launch(void* const* d_in, const int* in_sizes, int n_in,
                              void* d_out, int out_size, void* d_ws, size_t ws_size,
                              hipStream_t stream) {
    const int4*   vcoords = (const int4*)d_in[0];
    const float4* kcoords = (const float4*)d_in[1];
    const float*  voxels  = (const float*)d_in[2];
    const float*  w1      = (const float*)d_in[3];
    const float*  b1      = (const float*)d_in[4];
    const float*  w2      = (const float*)d_in[5];
    const float*  b2      = (const float*)d_in[6];
    float* out = (float*)d_out;
    float* ws  = (float*)d_ws;
    ull* K64   = (ull*)((char*)d_ws + OFF_K64);

    partition_kernel<<<1, 1024, 0, stream>>>(vcoords, kcoords, ws);
    attn_kernel<<<256, 1024, 0, stream>>>(ws);
    mlp_kernel<<<32, 256, 0, stream>>>(ws, w1, b1, w2, b2, out + 102400, K64);
    rank_scatter_kernel<<<256, 1024, 0, stream>>>(K64, vcoords, voxels, out);
}